// Round 11
// baseline (248.437 us; speedup 1.0000x reference)
//
#include <hip/hip_runtime.h>

#define FD 128
#define SHIFT 10         // nodes per bucket = 1024
#define BNODES 1024
#define NBK 128          // padded bucket-array size (98 used)
#define CHUNK 4096       // edges per scatter block
#define ST 512           // scatter block threads
#define NE 8             // edges in flight per row-group in k_layer
#define DMAX 256         // degree bins for counting sort

typedef unsigned int u32;
typedef unsigned short u16;
typedef unsigned char u8;
typedef __attribute__((ext_vector_type(8))) short short8;   // 8 bf16 (4 VGPR)
typedef __attribute__((ext_vector_type(4))) float f32x4;
typedef __attribute__((ext_vector_type(4))) u32 u32x4;

__device__ inline u16 f2bf(float f) {            // fp32 -> bf16 RNE
  u32 u = __float_as_uint(f);
  u += 0x7fffu + ((u >> 16) & 1u);
  return (u16)(u >> 16);
}
__device__ inline float bf2f(u16 h) { return __uint_as_float((u32)h << 16); }

// ---------- pass 0: bucket histograms (dst incl self-loops; src real edges) ----------
__global__ __launch_bounds__(512) void k_hist(const int* __restrict__ src,
                                              const int* __restrict__ dst,
                                              int* __restrict__ bcntD,
                                              int* __restrict__ bcntS,
                                              int e, int n, int nbuck) {
  __shared__ int shD[NBK];
  __shared__ int shS[NBK];
  int tid = threadIdx.x;
  if (tid < NBK) { shD[tid] = 0; shS[tid] = 0; }
  __syncthreads();
  int total = e + n;
  for (int t = blockIdx.x * blockDim.x + tid; t < total; t += gridDim.x * blockDim.x) {
    if (t < e) {
      atomicAdd(&shD[dst[t] >> SHIFT], 1);
      atomicAdd(&shS[src[t] >> SHIFT], 1);
    } else {
      atomicAdd(&shD[(t - e) >> SHIFT], 1);
    }
  }
  __syncthreads();
  if (tid < nbuck) {
    if (shD[tid]) atomicAdd(&bcntD[tid], shD[tid]);
    if (shS[tid]) atomicAdd(&bcntS[tid], shS[tid]);
  }
}

// ---------- pass 1: scan both bucket arrays ----------
__global__ __launch_bounds__(NBK) void k_bscan(
    const int* __restrict__ bcntD, const int* __restrict__ bcntS,
    int* __restrict__ bbaseD, int* __restrict__ bcurD,
    int* __restrict__ bbaseS, int* __restrict__ bcurS,
    int nbuck, int totalD, int totalS) {
  __shared__ int shD[NBK];
  __shared__ int shS[NBK];
  int tid = threadIdx.x;
  int vD = (tid < nbuck) ? bcntD[tid] : 0;
  int vS = (tid < nbuck) ? bcntS[tid] : 0;
  shD[tid] = vD; shS[tid] = vS;
  __syncthreads();
  for (int off = 1; off < NBK; off <<= 1) {
    int aD = (tid >= off) ? shD[tid - off] : 0;
    int aS = (tid >= off) ? shS[tid - off] : 0;
    __syncthreads();
    shD[tid] += aD; shS[tid] += aS;
    __syncthreads();
  }
  if (tid < nbuck) {
    int exD = shD[tid] - vD; bbaseD[tid] = exD; bcurD[tid] = exD;
    int exS = shS[tid] - vS; bbaseS[tid] = exS; bcurS[tid] = exS;
  }
  if (tid == 0) { bbaseD[nbuck] = totalD; bbaseS[nbuck] = totalS; }
}

// ---------- pass 2: dual locality-aware scatter (dst-keyed u32, src-keyed u16) ----------
// NO per-node device atomics. pack: local_dst(10b) << 22 | src(22b)
__global__ __launch_bounds__(ST) void k_scatter(
    const int* __restrict__ src, const int* __restrict__ dst,
    int* __restrict__ bcurD, int* __restrict__ bcurS,
    u32* __restrict__ pairs, u16* __restrict__ pairs2,
    int e, int n, int nbuck) {
  __shared__ int histD[NBK], exclD[NBK], gbaseD[NBK], rankD[NBK];
  __shared__ int histS[NBK], exclS[NBK], gbaseS[NBK], rankS[NBK];
  __shared__ u32 stgv[CHUNK];
  __shared__ u8  stgb[CHUNK];
  __shared__ u16 stg2[CHUNK];
  __shared__ u8  stg2b[CHUNK];
  int tid = threadIdx.x;
  int c0 = blockIdx.x * CHUNK;
  int total = e + n;
  if (tid < NBK) { histD[tid] = 0; histS[tid] = 0; }
  __syncthreads();
  u32 pv_[8]; int bD_[8], bS_[8]; bool v_[8], vs_[8];
  #pragma unroll
  for (int i = 0; i < 8; ++i) {
    int t = c0 + i * ST + tid;
    v_[i] = (t < total);
    vs_[i] = (t < e);
    pv_[i] = 0; bD_[i] = 0; bS_[i] = 0;
    if (v_[i]) {
      int s, d;
      if (vs_[i]) { s = src[t]; d = dst[t]; }
      else        { s = t - e;  d = s; }
      pv_[i] = ((u32)(d & (BNODES - 1)) << 22) | (u32)s;
      bD_[i] = d >> SHIFT;
      atomicAdd(&histD[bD_[i]], 1);
      if (vs_[i]) { bS_[i] = s >> SHIFT; atomicAdd(&histS[bS_[i]], 1); }
    }
  }
  __syncthreads();
  int hD = 0, hS = 0;
  if (tid < NBK) { hD = histD[tid]; hS = histS[tid]; }
  __syncthreads();
  for (int off = 1; off < NBK; off <<= 1) {
    int aD = 0, aS = 0;
    if (tid < NBK && tid >= off) { aD = histD[tid - off]; aS = histS[tid - off]; }
    __syncthreads();
    if (tid < NBK) { histD[tid] += aD; histS[tid] += aS; }
    __syncthreads();
  }
  if (tid < NBK) {
    int exD = histD[tid] - hD; exclD[tid] = exD; rankD[tid] = exD;
    int exS = histS[tid] - hS; exclS[tid] = exS; rankS[tid] = exS;
    gbaseD[tid] = (tid < nbuck && hD > 0) ? atomicAdd(&bcurD[tid], hD) : 0;
    gbaseS[tid] = (tid < nbuck && hS > 0) ? atomicAdd(&bcurS[tid], hS) : 0;
  }
  __syncthreads();
  #pragma unroll
  for (int i = 0; i < 8; ++i) {
    if (v_[i]) {
      int p = atomicAdd(&rankD[bD_[i]], 1);
      stgv[p] = pv_[i];
      stgb[p] = (u8)bD_[i];
    }
    if (vs_[i]) {
      int p = atomicAdd(&rankS[bS_[i]], 1);
      stg2[p] = (u16)(pv_[i] & (BNODES - 1));   // local src id
      stg2b[p] = (u8)bS_[i];
    }
  }
  __syncthreads();
  int V = min(CHUNK, total - c0);
  for (int j = tid; j < V; j += ST) {
    int b = stgb[j];
    pairs[gbaseD[b] + (j - exclD[b])] = stgv[j];   // contiguous runs per bucket
  }
  int V2 = min(CHUNK, e - c0);                     // negative -> loop skipped
  for (int j = tid; j < V2; j += ST) {
    int b = stg2b[j];
    pairs2[gbaseS[b] + (j - exclS[b])] = stg2[j];
  }
}

// ---------- pass 3: merged per-bucket finalize ----------
// blocks [0, nbuck): CSR (rp, col, nin, deg16, dhist) from dst-keyed pairs
// blocks [nbuck, 2*nbuck): out-degree -> nout from src-keyed pairs2
__global__ __launch_bounds__(1024) void k_build(
    const u32* __restrict__ pairs, const int* __restrict__ bbase,
    const u16* __restrict__ pairs2, const int* __restrict__ bbaseS,
    int* __restrict__ rp, int* __restrict__ col,
    float* __restrict__ nin, float* __restrict__ nout,
    u16* __restrict__ deg16, int* __restrict__ dhist,
    int n, int nbuck, int total) {
  __shared__ int cnt[BNODES];
  __shared__ int off_[BNODES];
  __shared__ int cur[BNODES];
  __shared__ int ddh[DMAX];
  int tid = threadIdx.x;            // 0..1023
  if (blockIdx.x >= (unsigned)nbuck) {
    // ---- build2: out-degree ----
    int b = blockIdx.x - nbuck;
    int base = bbaseS[b], end = bbaseS[b + 1];
    cnt[tid] = 0;
    __syncthreads();
    for (int t = base + tid; t < end; t += 1024)
      atomicAdd(&cnt[(int)pairs2[t]], 1);
    __syncthreads();
    int node = (b << SHIFT) + tid;
    if (node < n) nout[node] = rsqrtf((float)(cnt[tid] + 1));   // +1 self-loop
    return;
  }
  int b = blockIdx.x;
  int base = bbase[b], end = bbase[b + 1];
  int node0 = b << SHIFT;
  cnt[tid] = 0;
  if (tid < DMAX) ddh[tid] = 0;
  __syncthreads();
  for (int t = base + tid; t < end; t += 1024)
    atomicAdd(&cnt[(int)(pairs[t] >> 22)], 1);
  __syncthreads();
  int c = cnt[tid];
  off_[tid] = c;
  __syncthreads();
  for (int off = 1; off < BNODES; off <<= 1) {
    int add = (tid >= off) ? off_[tid - off] : 0;
    __syncthreads();
    off_[tid] += add;
    __syncthreads();
  }
  int ex = off_[tid] - c;
  int node = node0 + tid;
  if (node < n) {
    rp[node] = base + ex;
    nin[node] = rsqrtf((float)c);              // in-degree incl self-loop
    int dc = min(c, DMAX - 1);
    deg16[node] = (u16)dc;
    atomicAdd(&ddh[dc], 1);
  }
  if (b == nbuck - 1 && tid == 0) rp[n] = total;
  cur[tid] = ex;
  __syncthreads();
  if (tid < DMAX && ddh[tid]) atomicAdd(&dhist[tid], ddh[tid]);
  for (int t = base + tid; t < end; t += 1024) {
    u32 pr = pairs[t];
    int p = atomicAdd(&cur[(int)(pr >> 22)], 1);
    col[base + p] = (int)(pr & 0x3FFFFFu);
  }
}

// ---------- degree-histogram scan -> cursors ----------
__global__ __launch_bounds__(DMAX) void k_dscan(const int* __restrict__ dhist,
                                                int* __restrict__ dcur) {
  __shared__ int sh[DMAX];
  int tid = threadIdx.x;
  int v = dhist[tid];
  sh[tid] = v;
  __syncthreads();
  for (int off = 1; off < DMAX; off <<= 1) {
    int a = (tid >= off) ? sh[tid - off] : 0;
    __syncthreads();
    sh[tid] += a;
    __syncthreads();
  }
  dcur[tid] = sh[tid] - v;   // exclusive
}

// ---------- counting-sort permutation: perm = nodes ordered by degree ----------
__global__ __launch_bounds__(1024) void k_perm(const u16* __restrict__ deg16,
                                               int* __restrict__ dcur,
                                               int* __restrict__ perm, int n) {
  __shared__ int lh[DMAX], lb[DMAX], lr2[DMAX];
  int tid = threadIdx.x;
  int node = blockIdx.x * 1024 + tid;
  int d = (node < n) ? (int)deg16[node] : -1;
  if (tid < DMAX) { lh[tid] = 0; lr2[tid] = 0; }
  __syncthreads();
  if (d >= 0) atomicAdd(&lh[d], 1);
  __syncthreads();
  if (tid < DMAX && lh[tid]) lb[tid] = atomicAdd(&dcur[tid], lh[tid]);
  __syncthreads();
  if (d >= 0) {
    int rk = atomicAdd(&lr2[d], 1);
    perm[lb[d] + rk] = node;
  }
}

// ---------- pre-scale x by norm_out -> bf16; also zero the sentinel row n ----------
__global__ __launch_bounds__(256) void k_prescale(
    const float* __restrict__ x, const float* __restrict__ nout,
    u32* __restrict__ xs, int n) {
  int tot = (n + 1) * 64;   // float2 elements, incl zero row
  const float2* xv = (const float2*)x;
  for (int idx = blockIdx.x * blockDim.x + threadIdx.x; idx < tot;
       idx += gridDim.x * blockDim.x) {
    int row = idx >> 6;
    if (row >= n) { xs[idx] = 0; }
    else {
      float w = nout[row];
      float2 v = xv[idx];
      xs[idx] = (u32)f2bf(v.x * w) | ((u32)f2bf(v.y * w) << 16);
    }
  }
}

// ---------- W -> fragment-ordered split-bf16 (hi/lo planes); both W1 and W2 ----------
__global__ void k_prepw(const float* __restrict__ W1, u32* __restrict__ wf1hi,
                        u32* __restrict__ wf1lo,
                        const float* __restrict__ W2, u32* __restrict__ wf2hi,
                        u32* __restrict__ wf2lo) {
  int gi = blockIdx.x * 256 + threadIdx.x;   // 2 x 8192
  int i = gi & 8191;
  const float* W = (gi < 8192) ? W1 : W2;
  u32* wfhi = (gi < 8192) ? wf1hi : wf2hi;
  u32* wflo = (gi < 8192) ? wf1lo : wf2lo;
  int m = i & 3, l = (i >> 2) & 63, f = i >> 8;
  int kt = f & 3, nt = f >> 2;
  int k0 = kt * 32 + ((l >> 4) << 3) + 2 * m;
  int c = nt * 16 + (l & 15);
  float w0 = W[k0 * FD + c], w1 = W[(k0 + 1) * FD + c];
  u16 h0 = f2bf(w0), h1 = f2bf(w1);
  u16 l0 = f2bf(w0 - bf2f(h0)), l1 = f2bf(w1 - bf2f(h1));
  wfhi[i] = (u32)h0 | ((u32)h1 << 16);
  wflo[i] = (u32)l0 | ((u32)l1 << 16);
}

// ---------- fused layer over degree-sorted rows ----------
// Block b handles logical rows perm[16b .. 16b+16): all ~equal degree, so
// the pre-GEMM barrier costs ~nothing and sentinel-pad waste ~0.
__global__ __launch_bounds__(256) void k_layer(
    const u32* __restrict__ hs, const int* __restrict__ rp,
    const int* __restrict__ col, const float* __restrict__ nin,
    const int* __restrict__ perm,
    const u32* __restrict__ wfhi, const u32* __restrict__ wflo,
    const float* __restrict__ bias, const float* __restrict__ nout,
    float* __restrict__ fout, u32* __restrict__ hsout, int n, int mode) {
  __shared__ u32 As[1024];   // 16 rows x 256B (swizzled); reused for mode-1 staging
  int tid = threadIdx.x;
  int lane = tid & 63;
  int wv = tid >> 6;
  int g = lane >> 4, ch = lane & 15;
  int r0 = blockIdx.x * 16;
  int lr = wv * 4 + g;            // local row 0..15
  int rl = r0 + lr;               // logical (sorted) row
  bool valid = (rl < n);
  int row = valid ? perm[rl] : n;

  // ---- aggregation phase ----
  int e0 = 0, e1 = 0;
  if (valid) { e0 = rp[row]; e1 = rp[row + 1]; }   // e1 > e0 (self-loop)
  int m = e1 - e0;
  m = max(m, __shfl_xor(m, 16, 64));
  m = max(m, __shfl_xor(m, 32, 64));
  int trips = (m + NE - 1) / NE;
  float acc[8] = {0.f, 0.f, 0.f, 0.f, 0.f, 0.f, 0.f, 0.f};
  const u32x4* hv = (const u32x4*)hs;   // 16 chunks per row
  int em1 = (e1 > 0) ? (e1 - 1) : 0;

  int cs[NE], csn[NE];
  #pragma unroll
  for (int u = 0; u < NE; ++u) cs[u] = col[min(e0 + u, em1)];
  for (int it = 0; it < trips; ++it) {
    int tb = e0 + it * NE;
    u32x4 buf[NE];
    #pragma unroll
    for (int u = 0; u < NE; ++u) {
      int s = (tb + u < e1) ? cs[u] : n;   // sentinel zero row for pads
      buf[u] = hv[(size_t)s * 16 + ch];
    }
    #pragma unroll
    for (int u = 0; u < NE; ++u) csn[u] = col[min(tb + NE + u, em1)];
    __builtin_amdgcn_sched_barrier(0);     // all NE gathers + next cols issued first
    #pragma unroll
    for (int u = 0; u < NE; ++u)
      #pragma unroll
      for (int j = 0; j < 4; ++j) {
        u32 x = buf[u][j];
        acc[2 * j]     += __uint_as_float(x << 16);
        acc[2 * j + 1] += __uint_as_float(x & 0xFFFF0000u);
      }
    #pragma unroll
    for (int u = 0; u < NE; ++u) cs[u] = csn[u];
  }
  float wi = valid ? nin[row] : 0.f;
  u32 hi[4];
  #pragma unroll
  for (int j = 0; j < 4; ++j) {
    float v0 = acc[2 * j] * wi, v1 = acc[2 * j + 1] * wi;
    hi[j] = (u32)f2bf(v0) | ((u32)f2bf(v1) << 16);
  }
  int sch = ch ^ (lr & 7);                 // 16B-chunk XOR swizzle
  u32x4 hq = {hi[0], hi[1], hi[2], hi[3]};
  *(u32x4*)(As + lr * 64 + sch * 4) = hq;
  __syncthreads();

  // ---- GEMM phase ----
  short8 afh[4];
  int arow = lane & 15;
  #pragma unroll
  for (int kt = 0; kt < 4; ++kt) {
    int boff = arow * 256 + ((kt * 64 + (lane >> 4) * 16) ^ ((arow & 7) << 4));
    afh[kt] = *(const short8*)((const char*)As + boff);
  }
  __syncthreads();   // all waves hold their A-frags; As is now dead (mode-1 reuse)

  #pragma unroll
  for (int q = 0; q < 2; ++q) {
    int nt = wv * 2 + q;
    f32x4 oacc = {0.f, 0.f, 0.f, 0.f};
    #pragma unroll
    for (int kt = 0; kt < 4; ++kt) {
      int f = nt * 4 + kt;
      short8 wh = *(const short8*)(wfhi + (size_t)(f * 64 + lane) * 4);
      short8 wl = *(const short8*)(wflo + (size_t)(f * 64 + lane) * 4);
      oacc = __builtin_amdgcn_mfma_f32_16x16x32_bf16(afh[kt], wh, oacc, 0, 0, 0);
      oacc = __builtin_amdgcn_mfma_f32_16x16x32_bf16(afh[kt], wl, oacc, 0, 0, 0);
    }
    int c = nt * 16 + (lane & 15);
    float bv = bias[c];
    int rbase = r0 + (lane >> 4) * 4;   // logical rows; C/D: col=lane&15, row idx j
    if (mode == 0) {
      #pragma unroll
      for (int j = 0; j < 4; ++j) {
        int rl2 = rbase + j;
        if (rl2 < n) fout[(size_t)perm[rl2] * FD + c] = oacc[j] + bv;
      }
    } else {
      // stage bf16 into As (natural layout) for coalesced stores
      #pragma unroll
      for (int j = 0; j < 4; ++j) {
        int rl2 = rbase + j;
        float w = (rl2 < n) ? nout[perm[rl2]] : 0.f;
        ((u16*)As)[(rl2 - r0) * 128 + c] = f2bf((oacc[j] + bv) * w);
      }
    }
  }
  if (mode == 1) {
    __syncthreads();
    int lrow = tid >> 4, chk = tid & 15;
    int rl2 = r0 + lrow;
    if (rl2 < n)
      *(u32x4*)(hsout + (size_t)perm[rl2] * 64 + chk * 4) =
          *(const u32x4*)(As + lrow * 64 + chk * 4);
  }
}

// ---------------- launch ----------------
extern "C" void kernel_launch(void* const* d_in, const int* in_sizes, int n_in,
                              void* d_out, int out_size, void* d_ws, size_t ws_size,
                              hipStream_t stream) {
  const float* x  = (const float*)d_in[0];
  const int* src  = (const int*)d_in[1];
  const int* dst  = (const int*)d_in[2];
  const float* W1 = (const float*)d_in[3];
  const float* b1 = (const float*)d_in[4];
  const float* W2 = (const float*)d_in[5];
  const float* b2 = (const float*)d_in[6];
  float* out = (float*)d_out;

  int n = in_sizes[0] / FD;      // 100000
  int e = in_sizes[1];           // 1600000
  int total = e + n;
  int nbuck = (n + BNODES - 1) >> SHIFT;   // 98

  char* ws = (char*)d_ws;
  size_t off = 0;
  auto alloc = [&](size_t bytes) -> void* {
    void* p = ws + off;
    off += (bytes + 255) / 256 * 256;
    return p;
  };
  // xs region also hosts pairs (dead before prescale writes xs)
  u32* xs    = (u32*)alloc((size_t)(n + 16) * 64 * 4);   // 25.6 MB
  u32* pairs = xs;
  u32* h1s   = (u32*)alloc((size_t)(n + 16) * 64 * 4);   // 25.6 MB (own buffer)
  u16* pairs2 = (u16*)alloc((size_t)e * 2 + 256);        // 3.2 MB (src-keyed)
  int* col   = (int*)alloc((size_t)total * 4 + 256);     // 6.8 MB (+tail slack)
  int* rp    = (int*)alloc((size_t)(n + 1) * 4);
  float* nin  = (float*)alloc((size_t)n * 4);
  float* nout = (float*)alloc((size_t)n * 4);
  u16* deg16  = (u16*)alloc((size_t)n * 2);
  int* perm   = (int*)alloc((size_t)n * 4);
  int* bcntD  = (int*)alloc(NBK * 4);       // NBK*4 = 512B: keeps next allocs contiguous
  int* bcntS  = (int*)alloc(NBK * 4);
  int* dhist  = (int*)alloc(DMAX * 4);
  int* dcur   = (int*)alloc(DMAX * 4);
  int* bbaseD = (int*)alloc((NBK + 1) * 4);
  int* bbaseS = (int*)alloc((NBK + 1) * 4);
  int* bcurD  = (int*)alloc(NBK * 4);
  int* bcurS  = (int*)alloc(NBK * 4);
  u32* wf1hi  = (u32*)alloc(8192 * 4);
  u32* wf1lo  = (u32*)alloc(8192 * 4);
  u32* wf2hi  = (u32*)alloc(8192 * 4);
  u32* wf2lo  = (u32*)alloc(8192 * 4);

  // bcntD, bcntS, dhist are contiguous 256B-aligned chunks: one memset
  hipMemsetAsync(bcntD, 0, (size_t)(NBK * 2 + DMAX) * 4, stream);
  hipMemsetAsync(h1s + (size_t)n * 64, 0, FD * 2, stream); // h1s sentinel row

  k_hist<<<256, 512, 0, stream>>>(src, dst, bcntD, bcntS, e, n, nbuck);
  k_bscan<<<1, NBK, 0, stream>>>(bcntD, bcntS, bbaseD, bcurD, bbaseS, bcurS,
                                 nbuck, total, e);
  k_scatter<<<(total + CHUNK - 1) / CHUNK, ST, 0, stream>>>(
      src, dst, bcurD, bcurS, pairs, pairs2, e, n, nbuck);
  k_build<<<2 * nbuck, 1024, 0, stream>>>(pairs, bbaseD, pairs2, bbaseS,
                                          rp, col, nin, nout, deg16, dhist,
                                          n, nbuck, total);
  k_dscan<<<1, DMAX, 0, stream>>>(dhist, dcur);
  k_perm<<<nbuck, 1024, 0, stream>>>(deg16, dcur, perm, n);
  k_prepw<<<64, 256, 0, stream>>>(W1, wf1hi, wf1lo, W2, wf2hi, wf2lo);
  k_prescale<<<2048, 256, 0, stream>>>(x, nout, xs, n);

  int lgrid = (n + 15) / 16;     // 6250 blocks, 16 sorted rows each
  // layer 1: gathers xs, writes h1s (separate buffer -> no race)
  k_layer<<<lgrid, 256, 0, stream>>>(xs, rp, col, nin, perm, wf1hi, wf1lo, b1,
                                     nout, nullptr, h1s, n, 1);
  // layer 2: gathers h1s, writes fp32 out
  k_layer<<<lgrid, 256, 0, stream>>>(h1s, rp, col, nin, perm, wf2hi, wf2lo,
                                     b2, nout, out, nullptr, n, 0);
}

// Round 12
// 235.449 us; speedup vs baseline: 1.0552x; 1.0552x over previous
//
#include <hip/hip_runtime.h>

#define FD 128
#define SHIFT 10         // nodes per bucket = 1024
#define BNODES 1024
#define NBK 128          // padded bucket-array size (98 used)
#define CHUNK 4096       // edges per scatter block
#define ST 512           // scatter block threads
#define NE 8             // edges in flight per row-group in k_layer

typedef unsigned int u32;
typedef unsigned short u16;
typedef unsigned char u8;
typedef __attribute__((ext_vector_type(8))) short short8;   // 8 bf16 (4 VGPR)
typedef __attribute__((ext_vector_type(4))) float f32x4;
typedef __attribute__((ext_vector_type(4))) u32 u32x4;

__device__ inline u16 f2bf(float f) {            // fp32 -> bf16 RNE
  u32 u = __float_as_uint(f);
  u += 0x7fffu + ((u >> 16) & 1u);
  return (u16)(u >> 16);
}
__device__ inline float bf2f(u16 h) { return __uint_as_float((u32)h << 16); }

// ---------- pass 0: bucket histograms (dst incl self-loops; src real edges) ----------
__global__ __launch_bounds__(512) void k_hist(const int* __restrict__ src,
                                              const int* __restrict__ dst,
                                              int* __restrict__ bcntD,
                                              int* __restrict__ bcntS,
                                              int e, int n, int nbuck) {
  __shared__ int shD[NBK];
  __shared__ int shS[NBK];
  int tid = threadIdx.x;
  if (tid < NBK) { shD[tid] = 0; shS[tid] = 0; }
  __syncthreads();
  int total = e + n;
  for (int t = blockIdx.x * blockDim.x + tid; t < total; t += gridDim.x * blockDim.x) {
    if (t < e) {
      atomicAdd(&shD[dst[t] >> SHIFT], 1);
      atomicAdd(&shS[src[t] >> SHIFT], 1);
    } else {
      atomicAdd(&shD[(t - e) >> SHIFT], 1);
    }
  }
  __syncthreads();
  if (tid < nbuck) {
    if (shD[tid]) atomicAdd(&bcntD[tid], shD[tid]);
    if (shS[tid]) atomicAdd(&bcntS[tid], shS[tid]);
  }
}

// ---------- pass 1: scan both bucket arrays ----------
__global__ __launch_bounds__(NBK) void k_bscan(
    const int* __restrict__ bcntD, const int* __restrict__ bcntS,
    int* __restrict__ bbaseD, int* __restrict__ bcurD,
    int* __restrict__ bbaseS, int* __restrict__ bcurS,
    int nbuck, int totalD, int totalS) {
  __shared__ int shD[NBK];
  __shared__ int shS[NBK];
  int tid = threadIdx.x;
  int vD = (tid < nbuck) ? bcntD[tid] : 0;
  int vS = (tid < nbuck) ? bcntS[tid] : 0;
  shD[tid] = vD; shS[tid] = vS;
  __syncthreads();
  for (int off = 1; off < NBK; off <<= 1) {
    int aD = (tid >= off) ? shD[tid - off] : 0;
    int aS = (tid >= off) ? shS[tid - off] : 0;
    __syncthreads();
    shD[tid] += aD; shS[tid] += aS;
    __syncthreads();
  }
  if (tid < nbuck) {
    int exD = shD[tid] - vD; bbaseD[tid] = exD; bcurD[tid] = exD;
    int exS = shS[tid] - vS; bbaseS[tid] = exS; bcurS[tid] = exS;
  }
  if (tid == 0) { bbaseD[nbuck] = totalD; bbaseS[nbuck] = totalS; }
}

// ---------- pass 2: dual locality-aware scatter (dst-keyed u32, src-keyed u16) ----------
// NO per-node device atomics. pack: local_dst(10b) << 22 | src(22b)
__global__ __launch_bounds__(ST) void k_scatter(
    const int* __restrict__ src, const int* __restrict__ dst,
    int* __restrict__ bcurD, int* __restrict__ bcurS,
    u32* __restrict__ pairs, u16* __restrict__ pairs2,
    int e, int n, int nbuck) {
  __shared__ int histD[NBK], exclD[NBK], gbaseD[NBK], rankD[NBK];
  __shared__ int histS[NBK], exclS[NBK], gbaseS[NBK], rankS[NBK];
  __shared__ u32 stgv[CHUNK];
  __shared__ u8  stgb[CHUNK];
  __shared__ u16 stg2[CHUNK];
  __shared__ u8  stg2b[CHUNK];
  int tid = threadIdx.x;
  int c0 = blockIdx.x * CHUNK;
  int total = e + n;
  if (tid < NBK) { histD[tid] = 0; histS[tid] = 0; }
  __syncthreads();
  u32 pv_[8]; int bD_[8], bS_[8]; bool v_[8], vs_[8];
  #pragma unroll
  for (int i = 0; i < 8; ++i) {
    int t = c0 + i * ST + tid;
    v_[i] = (t < total);
    vs_[i] = (t < e);
    pv_[i] = 0; bD_[i] = 0; bS_[i] = 0;
    if (v_[i]) {
      int s, d;
      if (vs_[i]) { s = src[t]; d = dst[t]; }
      else        { s = t - e;  d = s; }
      pv_[i] = ((u32)(d & (BNODES - 1)) << 22) | (u32)s;
      bD_[i] = d >> SHIFT;
      atomicAdd(&histD[bD_[i]], 1);
      if (vs_[i]) { bS_[i] = s >> SHIFT; atomicAdd(&histS[bS_[i]], 1); }
    }
  }
  __syncthreads();
  int hD = 0, hS = 0;
  if (tid < NBK) { hD = histD[tid]; hS = histS[tid]; }
  __syncthreads();
  for (int off = 1; off < NBK; off <<= 1) {
    int aD = 0, aS = 0;
    if (tid < NBK && tid >= off) { aD = histD[tid - off]; aS = histS[tid - off]; }
    __syncthreads();
    if (tid < NBK) { histD[tid] += aD; histS[tid] += aS; }
    __syncthreads();
  }
  if (tid < NBK) {
    int exD = histD[tid] - hD; exclD[tid] = exD; rankD[tid] = exD;
    int exS = histS[tid] - hS; exclS[tid] = exS; rankS[tid] = exS;
    gbaseD[tid] = (tid < nbuck && hD > 0) ? atomicAdd(&bcurD[tid], hD) : 0;
    gbaseS[tid] = (tid < nbuck && hS > 0) ? atomicAdd(&bcurS[tid], hS) : 0;
  }
  __syncthreads();
  #pragma unroll
  for (int i = 0; i < 8; ++i) {
    if (v_[i]) {
      int p = atomicAdd(&rankD[bD_[i]], 1);
      stgv[p] = pv_[i];
      stgb[p] = (u8)bD_[i];
    }
    if (vs_[i]) {
      int p = atomicAdd(&rankS[bS_[i]], 1);
      stg2[p] = (u16)(pv_[i] & (BNODES - 1));   // local src id
      stg2b[p] = (u8)bS_[i];
    }
  }
  __syncthreads();
  int V = min(CHUNK, total - c0);
  for (int j = tid; j < V; j += ST) {
    int b = stgb[j];
    pairs[gbaseD[b] + (j - exclD[b])] = stgv[j];   // contiguous runs per bucket
  }
  int V2 = min(CHUNK, e - c0);                     // negative -> loop skipped
  for (int j = tid; j < V2; j += ST) {
    int b = stg2b[j];
    pairs2[gbaseS[b] + (j - exclS[b])] = stg2[j];
  }
}

// ---------- pass 3: merged per-bucket finalize ----------
// blocks [0, nbuck): CSR (rp, col, nin) from dst-keyed pairs
// blocks [nbuck, 2*nbuck): out-degree -> nout from src-keyed pairs2
__global__ __launch_bounds__(1024) void k_build(
    const u32* __restrict__ pairs, const int* __restrict__ bbase,
    const u16* __restrict__ pairs2, const int* __restrict__ bbaseS,
    int* __restrict__ rp, int* __restrict__ col,
    float* __restrict__ nin, float* __restrict__ nout,
    int n, int nbuck, int total) {
  __shared__ int cnt[BNODES];
  __shared__ int off_[BNODES];
  __shared__ int cur[BNODES];
  int tid = threadIdx.x;            // 0..1023
  if (blockIdx.x >= (unsigned)nbuck) {
    // ---- build2: out-degree ----
    int b = blockIdx.x - nbuck;
    int base = bbaseS[b], end = bbaseS[b + 1];
    cnt[tid] = 0;
    __syncthreads();
    for (int t = base + tid; t < end; t += 1024)
      atomicAdd(&cnt[(int)pairs2[t]], 1);
    __syncthreads();
    int node = (b << SHIFT) + tid;
    if (node < n) nout[node] = rsqrtf((float)(cnt[tid] + 1));   // +1 self-loop
    return;
  }
  int b = blockIdx.x;
  int base = bbase[b], end = bbase[b + 1];
  int node0 = b << SHIFT;
  cnt[tid] = 0;
  __syncthreads();
  for (int t = base + tid; t < end; t += 1024)
    atomicAdd(&cnt[(int)(pairs[t] >> 22)], 1);
  __syncthreads();
  int c = cnt[tid];
  off_[tid] = c;
  __syncthreads();
  for (int off = 1; off < BNODES; off <<= 1) {
    int add = (tid >= off) ? off_[tid - off] : 0;
    __syncthreads();
    off_[tid] += add;
    __syncthreads();
  }
  int ex = off_[tid] - c;
  int node = node0 + tid;
  if (node < n) {
    rp[node] = base + ex;
    nin[node] = rsqrtf((float)c);              // in-degree incl self-loop
  }
  if (b == nbuck - 1 && tid == 0) rp[n] = total;
  cur[tid] = ex;
  __syncthreads();
  for (int t = base + tid; t < end; t += 1024) {
    u32 pr = pairs[t];
    int p = atomicAdd(&cur[(int)(pr >> 22)], 1);
    col[base + p] = (int)(pr & 0x3FFFFFu);
  }
}

// ---------- pre-scale x by norm_out -> bf16; also zero the sentinel row n ----------
__global__ __launch_bounds__(256) void k_prescale(
    const float* __restrict__ x, const float* __restrict__ nout,
    u32* __restrict__ xs, int n) {
  int tot = (n + 1) * 64;   // float2 elements, incl zero row
  const float2* xv = (const float2*)x;
  for (int idx = blockIdx.x * blockDim.x + threadIdx.x; idx < tot;
       idx += gridDim.x * blockDim.x) {
    int row = idx >> 6;
    if (row >= n) { xs[idx] = 0; }
    else {
      float w = nout[row];
      float2 v = xv[idx];
      xs[idx] = (u32)f2bf(v.x * w) | ((u32)f2bf(v.y * w) << 16);
    }
  }
}

// ---------- W -> fragment-ordered split-bf16 (hi/lo planes); both W1 and W2 ----------
__global__ void k_prepw(const float* __restrict__ W1, u32* __restrict__ wf1hi,
                        u32* __restrict__ wf1lo,
                        const float* __restrict__ W2, u32* __restrict__ wf2hi,
                        u32* __restrict__ wf2lo) {
  int gi = blockIdx.x * 256 + threadIdx.x;   // 2 x 8192
  int i = gi & 8191;
  const float* W = (gi < 8192) ? W1 : W2;
  u32* wfhi = (gi < 8192) ? wf1hi : wf2hi;
  u32* wflo = (gi < 8192) ? wf1lo : wf2lo;
  int m = i & 3, l = (i >> 2) & 63, f = i >> 8;
  int kt = f & 3, nt = f >> 2;
  int k0 = kt * 32 + ((l >> 4) << 3) + 2 * m;
  int c = nt * 16 + (l & 15);
  float w0 = W[k0 * FD + c], w1 = W[(k0 + 1) * FD + c];
  u16 h0 = f2bf(w0), h1 = f2bf(w1);
  u16 l0 = f2bf(w0 - bf2f(h0)), l1 = f2bf(w1 - bf2f(h1));
  wfhi[i] = (u32)h0 | ((u32)h1 << 16);
  wflo[i] = (u32)l0 | ((u32)l1 << 16);
}

// ---------- fused layer: PER-WAVE 16-row tile, no inter-wave coupling ----------
// Each wave: gather-aggregate 16 rows (4 batches x 4 rows, one row per 16-lane
// group, NE=8 gathers in flight) into its private 4KB LDS quadrant, then do
// the full 16x128 MFMA GEMM alone and write out. NO __syncthreads -> waves in
// gather phase keep the memory pipe saturated while others do GEMM.
// mode 0: fp32 out ; mode 1: bf16(nout*val), LDS-staged coalesced stores.
__global__ __launch_bounds__(256) void k_layer(
    const u32* __restrict__ hs, const int* __restrict__ rp,
    const int* __restrict__ col, const float* __restrict__ nin,
    const u32* __restrict__ wfhi, const u32* __restrict__ wflo,
    const float* __restrict__ bias, const float* __restrict__ nout,
    float* __restrict__ fout, u32* __restrict__ hsout, int n, int mode) {
  __shared__ u32 As[4096];        // 4 waves x 16 rows x 256B
  int tid = threadIdx.x;
  int lane = tid & 63;
  int wv = tid >> 6;
  int g = lane >> 4, ch = lane & 15;
  int wbase = (blockIdx.x * 4 + wv) * 16;   // this wave's 16-row tile
  u32* Aw = As + wv * 1024;
  const u32x4* hv = (const u32x4*)hs;       // 16 chunks per row

  // ---- aggregation: 4 batches of 4 rows ----
  #pragma unroll 1
  for (int b = 0; b < 4; ++b) {
    int lr = b * 4 + g;           // local row 0..15
    int r = wbase + lr;
    bool valid = (r < n);
    int e0 = 0, e1 = 0;
    if (valid) { e0 = rp[r]; e1 = rp[r + 1]; }   // e1 > e0 (self-loop)
    int m = e1 - e0;
    m = max(m, __shfl_xor(m, 16, 64));
    m = max(m, __shfl_xor(m, 32, 64));
    int trips = (m + NE - 1) / NE;
    float acc[8] = {0.f, 0.f, 0.f, 0.f, 0.f, 0.f, 0.f, 0.f};
    int em1 = (e1 > 0) ? (e1 - 1) : 0;
    int cs[NE], csn[NE];
    #pragma unroll
    for (int u = 0; u < NE; ++u) cs[u] = col[min(e0 + u, em1)];
    for (int it = 0; it < trips; ++it) {
      int tb = e0 + it * NE;
      u32x4 buf[NE];
      #pragma unroll
      for (int u = 0; u < NE; ++u) {
        int s = (tb + u < e1) ? cs[u] : n;   // sentinel zero row for pads
        buf[u] = hv[(size_t)s * 16 + ch];
      }
      #pragma unroll
      for (int u = 0; u < NE; ++u) csn[u] = col[min(tb + NE + u, em1)];
      __builtin_amdgcn_sched_barrier(0);     // all NE gathers + next cols issued first
      #pragma unroll
      for (int u = 0; u < NE; ++u)
        #pragma unroll
        for (int j = 0; j < 4; ++j) {
          u32 x = buf[u][j];
          acc[2 * j]     += __uint_as_float(x << 16);
          acc[2 * j + 1] += __uint_as_float(x & 0xFFFF0000u);
        }
      #pragma unroll
      for (int u = 0; u < NE; ++u) cs[u] = csn[u];
    }
    float wi = valid ? nin[r] : 0.f;
    u32 hi[4];
    #pragma unroll
    for (int j = 0; j < 4; ++j) {
      float v0 = acc[2 * j] * wi, v1 = acc[2 * j + 1] * wi;
      hi[j] = (u32)f2bf(v0) | ((u32)f2bf(v1) << 16);
    }
    int sch = ch ^ (lr & 7);                 // 16B-chunk XOR swizzle
    u32x4 hq = {hi[0], hi[1], hi[2], hi[3]};
    *(u32x4*)(Aw + lr * 64 + sch * 4) = hq;
  }

  // wave-internal LDS ordering: drain ds_writes before ds_reads (no barrier)
  asm volatile("s_waitcnt lgkmcnt(0)" ::: "memory");
  __builtin_amdgcn_sched_barrier(0);

  // ---- GEMM phase (this wave alone: 16 rows x 128 cols) ----
  short8 afh[4];
  int arow = lane & 15;
  #pragma unroll
  for (int kt = 0; kt < 4; ++kt) {
    int boff = arow * 256 + ((kt * 64 + (lane >> 4) * 16) ^ ((arow & 7) << 4));
    afh[kt] = *(const short8*)((const char*)Aw + boff);
  }

  float wout[4];
  int rb0 = wbase + (lane >> 4) * 4;   // C/D: col=lane&15, row=(lane>>4)*4+j
  if (mode == 1) {
    #pragma unroll
    for (int j = 0; j < 4; ++j)
      wout[j] = (rb0 + j < n) ? nout[rb0 + j] : 0.f;
  }

  #pragma unroll 1
  for (int nt = 0; nt < 8; ++nt) {
    f32x4 oacc = {0.f, 0.f, 0.f, 0.f};
    #pragma unroll
    for (int kt = 0; kt < 4; ++kt) {
      int f = nt * 4 + kt;
      short8 wh = *(const short8*)(wfhi + (size_t)(f * 64 + lane) * 4);
      short8 wl = *(const short8*)(wflo + (size_t)(f * 64 + lane) * 4);
      oacc = __builtin_amdgcn_mfma_f32_16x16x32_bf16(afh[kt], wh, oacc, 0, 0, 0);
      oacc = __builtin_amdgcn_mfma_f32_16x16x32_bf16(afh[kt], wl, oacc, 0, 0, 0);
    }
    int c = nt * 16 + (lane & 15);
    float bv = bias[c];
    if (mode == 0) {
      #pragma unroll
      for (int j = 0; j < 4; ++j) {
        int row = rb0 + j;
        if (row < n) fout[(size_t)row * FD + c] = oacc[j] + bv;
      }
    } else {
      // restage bf16 into Aw (natural row layout) for coalesced stores
      #pragma unroll
      for (int j = 0; j < 4; ++j) {
        int lr2 = (lane >> 4) * 4 + j;
        ((u16*)Aw)[lr2 * 128 + c] = f2bf((oacc[j] + bv) * wout[j]);
      }
    }
  }
  if (mode == 1) {
    asm volatile("s_waitcnt lgkmcnt(0)" ::: "memory");
    __builtin_amdgcn_sched_barrier(0);
    #pragma unroll
    for (int it = 0; it < 4; ++it) {
      int ci = it * 64 + lane;         // 0..255 : 16 rows x 16 chunks
      int lrow = ci >> 4, chk = ci & 15;
      int row = wbase + lrow;
      if (row < n)
        *(u32x4*)(hsout + (size_t)row * 64 + chk * 4) =
            *(const u32x4*)(Aw + lrow * 64 + chk * 4);
    }
  }
}

// ---------------- launch ----------------
extern "C" void kernel_launch(void* const* d_in, const int* in_sizes, int n_in,
                              void* d_out, int out_size, void* d_ws, size_t ws_size,
                              hipStream_t stream) {
  const float* x  = (const float*)d_in[0];
  const int* src  = (const int*)d_in[1];
  const int* dst  = (const int*)d_in[2];
  const float* W1 = (const float*)d_in[3];
  const float* b1 = (const float*)d_in[4];
  const float* W2 = (const float*)d_in[5];
  const float* b2 = (const float*)d_in[6];
  float* out = (float*)d_out;

  int n = in_sizes[0] / FD;      // 100000
  int e = in_sizes[1];           // 1600000
  int total = e + n;
  int nbuck = (n + BNODES - 1) >> SHIFT;   // 98

  char* ws = (char*)d_ws;
  size_t off = 0;
  auto alloc = [&](size_t bytes) -> void* {
    void* p = ws + off;
    off += (bytes + 255) / 256 * 256;
    return p;
  };
  // xs region also hosts pairs (dead before prescale writes xs)
  u32* xs    = (u32*)alloc((size_t)(n + 16) * 64 * 4);   // 25.6 MB
  u32* pairs = xs;
  u32* h1s   = (u32*)alloc((size_t)(n + 16) * 64 * 4);   // 25.6 MB (own buffer)
  u16* pairs2 = (u16*)alloc((size_t)e * 2 + 256);        // 3.2 MB (src-keyed)
  int* col   = (int*)alloc((size_t)total * 4 + 256);     // 6.8 MB (+tail slack)
  int* rp    = (int*)alloc((size_t)(n + 1) * 4);
  float* nin  = (float*)alloc((size_t)n * 4);
  float* nout = (float*)alloc((size_t)n * 4);
  int* bcntD  = (int*)alloc(NBK * 4);
  int* bcntS  = (int*)alloc(NBK * 4);
  int* bbaseD = (int*)alloc((NBK + 1) * 4);
  int* bbaseS = (int*)alloc((NBK + 1) * 4);
  int* bcurD  = (int*)alloc(NBK * 4);
  int* bcurS  = (int*)alloc(NBK * 4);
  u32* wf1hi  = (u32*)alloc(8192 * 4);
  u32* wf1lo  = (u32*)alloc(8192 * 4);
  u32* wf2hi  = (u32*)alloc(8192 * 4);
  u32* wf2lo  = (u32*)alloc(8192 * 4);

  hipMemsetAsync(bcntD, 0, (size_t)NBK * 4 * 2, stream);   // bcntD+bcntS contiguous
  hipMemsetAsync(h1s + (size_t)n * 64, 0, FD * 2, stream); // h1s sentinel row

  k_hist<<<256, 512, 0, stream>>>(src, dst, bcntD, bcntS, e, n, nbuck);
  k_bscan<<<1, NBK, 0, stream>>>(bcntD, bcntS, bbaseD, bcurD, bbaseS, bcurS,
                                 nbuck, total, e);
  k_scatter<<<(total + CHUNK - 1) / CHUNK, ST, 0, stream>>>(
      src, dst, bcurD, bcurS, pairs, pairs2, e, n, nbuck);
  k_build<<<2 * nbuck, 1024, 0, stream>>>(pairs, bbaseD, pairs2, bbaseS,
                                          rp, col, nin, nout, n, nbuck, total);
  k_prepw<<<64, 256, 0, stream>>>(W1, wf1hi, wf1lo, W2, wf2hi, wf2lo);
  k_prescale<<<2048, 256, 0, stream>>>(x, nout, xs, n);

  int lgrid = (n + 63) / 64;     // 1563 blocks; 4 independent 16-row wave-tiles each
  // layer 1: gathers xs, writes h1s (separate buffer -> no race)
  k_layer<<<lgrid, 256, 0, stream>>>(xs, rp, col, nin, wf1hi, wf1lo, b1, nout,
                                     nullptr, h1s, n, 1);
  // layer 2: gathers h1s, writes fp32 out
  k_layer<<<lgrid, 256, 0, stream>>>(h1s, rp, col, nin, wf2hi, wf2lo,
                                     b2, nout, out, nullptr, n, 0);
}